// Round 3
// baseline (742.276 us; speedup 1.0000x reference)
//
#include <hip/hip_runtime.h>
#include <hip/hip_bf16.h>

typedef __bf16 bf16;
typedef __bf16 bf16x4 __attribute__((ext_vector_type(4)));
typedef __bf16 bf16x8 __attribute__((ext_vector_type(8)));
typedef float f32x4 __attribute__((ext_vector_type(4)));

#define TOK 100352   // 2048 windows * 49 tokens
#define ATT_SCALE 0.125f

// ---------------- weight transpose + cast: out[c][r] = bf16(in[r][c]) ----------------
__global__ __launch_bounds__(256) void transpose_cast_k(const float* __restrict__ in,
                                                        bf16* __restrict__ out, int R, int C) {
  __shared__ float t[32][33];
  int c0 = blockIdx.x * 32, r0 = blockIdx.y * 32;
  int tx = threadIdx.x, ty = threadIdx.y;
#pragma unroll
  for (int i = ty; i < 32; i += 8)
    t[i][tx] = in[(size_t)(r0 + i) * C + c0 + tx];
  __syncthreads();
#pragma unroll
  for (int i = ty; i < 32; i += 8)
    out[(size_t)(c0 + i) * R + r0 + tx] = (bf16)t[tx][i];
}

// ---------------- window partition + cast: A[tok_local][256] = bf16(fmap[...]) ----------------
__global__ __launch_bounds__(256) void cast_partition_k(const float* __restrict__ fmap,
                                                        bf16* __restrict__ A, int tok0) {
  int tid = blockIdx.x * 256 + threadIdx.x;
  int tokl = tid >> 5, cg = (tid & 31) << 3;
  int tok = tok0 + tokl;
  int w = tok / 49, t = tok - w * 49;
  int p1 = t / 7, p2 = t - p1 * 7;
  int bb = w >> 6, xx = (w >> 3) & 7, yy = w & 7;
  size_t src = ((((size_t)bb * 56) + xx * 7 + p1) * 56 + yy * 7 + p2) * 256 + cg;
  float4 f0 = *(const float4*)(fmap + src);
  float4 f1 = *(const float4*)(fmap + src + 4);
  bf16x8 o;
  o[0] = (bf16)f0.x; o[1] = (bf16)f0.y; o[2] = (bf16)f0.z; o[3] = (bf16)f0.w;
  o[4] = (bf16)f1.x; o[5] = (bf16)f1.y; o[6] = (bf16)f1.z; o[7] = (bf16)f1.w;
  *(bf16x8*)(A + (size_t)tokl * 256 + cg) = o;
}

// ---------------- GEMM: C[M][ND] = A[M][KD] @ Bt[ND][KD]^T, 128x128 tile, BK=64 ----------------
// MFMA operands SWAPPED -> transposed fragment: out row = l15, out col = l4*4+reg
// => packed stores (bf16x4 8B for EPI1, float4 16B for EPI2).
// grid = (ND/128, M/128): bn on fast axis so A-tile re-readers are concurrent.
template <int KD, int ND, int EPI>
__global__ __launch_bounds__(256) void gemm_bt_k(const bf16* __restrict__ A,
                                                 const bf16* __restrict__ Bt,
                                                 bf16* __restrict__ Cb, float* __restrict__ Cf,
                                                 const float* __restrict__ bias, int tok0) {
  __shared__ bf16 As[128 * 64], Bs[128 * 64];
  const int tid = threadIdx.x;
  const int lane = tid & 63, wv = tid >> 6;
  const int l15 = lane & 15, l4 = lane >> 4;
  const int bn = blockIdx.x, bm = blockIdx.y;
  const int mb = (wv >> 1) * 64, nb = (wv & 1) * 64;
  f32x4 acc[4][4] = {};
  for (int ks = 0; ks < KD / 64; ++ks) {
    uint4 ra[4], rb[4];
#pragma unroll
    for (int i = 0; i < 4; ++i) {
      int j = i * 256 + tid, r = j >> 3, cc = j & 7;
      ra[i] = *(const uint4*)(A + (size_t)(bm * 128 + r) * KD + ks * 64 + cc * 8);
      rb[i] = *(const uint4*)(Bt + (size_t)(bn * 128 + r) * KD + ks * 64 + cc * 8);
    }
    __syncthreads();  // previous tile's compute done before overwrite
#pragma unroll
    for (int i = 0; i < 4; ++i) {
      int j = i * 256 + tid, r = j >> 3, cc = j & 7;
      int off = (r * 128 + cc * 16) ^ ((r & 7) << 4);  // XOR swizzle, 16B granules
      *(uint4*)((char*)As + off) = ra[i];
      *(uint4*)((char*)Bs + off) = rb[i];
    }
    __syncthreads();
#pragma unroll
    for (int kk = 0; kk < 2; ++kk) {
      bf16x8 af[4], bfr[4];
#pragma unroll
      for (int m = 0; m < 4; ++m) {
        int r = mb + m * 16 + l15;
        af[m] = *(const bf16x8*)((const char*)As +
                 ((r * 128 + kk * 64 + l4 * 16) ^ ((r & 7) << 4)));
      }
#pragma unroll
      for (int n = 0; n < 4; ++n) {
        int r = nb + n * 16 + l15;
        bfr[n] = *(const bf16x8*)((const char*)Bs +
                 ((r * 128 + kk * 64 + l4 * 16) ^ ((r & 7) << 4)));
      }
#pragma unroll
      for (int m = 0; m < 4; ++m)
#pragma unroll
        for (int n = 0; n < 4; ++n)
          acc[m][n] = __builtin_amdgcn_mfma_f32_16x16x32_bf16(bfr[n], af[m], acc[m][n], 0, 0, 0);
    }
  }
  if constexpr (EPI == 1) {
#pragma unroll
    for (int m = 0; m < 4; ++m) {
      size_t row = (size_t)bm * 128 + mb + m * 16 + l15;
#pragma unroll
      for (int n = 0; n < 4; ++n) {
        int col = bn * 128 + nb + n * 16 + l4 * 4;
        bf16x4 pk;
#pragma unroll
        for (int r = 0; r < 4; ++r) pk[r] = (bf16)acc[m][n][r];
        *(bf16x4*)(Cb + row * ND + col) = pk;
      }
    }
  } else {
#pragma unroll
    for (int m = 0; m < 4; ++m) {
      int tok = tok0 + bm * 128 + mb + m * 16 + l15;
      int w = tok / 49, t = tok - w * 49;
      int p1 = t / 7, p2 = t - p1 * 7;
      int bb = w >> 6, xx = (w >> 3) & 7, yy = w & 7;
      size_t orow = (((size_t)bb * 56) + xx * 7 + p1) * 56 + yy * 7 + p2;
#pragma unroll
      for (int n = 0; n < 4; ++n) {
        int col = bn * 128 + nb + n * 16 + l4 * 4;
        float4 b4 = *(const float4*)(bias + col);
        float4 v;
        v.x = acc[m][n][0] + b4.x;
        v.y = acc[m][n][1] + b4.y;
        v.z = acc[m][n][2] + b4.z;
        v.w = acc[m][n][3] + b4.w;
        *(float4*)(Cf + orow * 256 + col) = v;
      }
    }
  }
}

// ---------------- attention: one block per (window_local, head) ----------------
__global__ __launch_bounds__(256) void attn_win_k(const bf16* __restrict__ qkv,
                                                  bf16* __restrict__ attn) {
  __shared__ bf16 Qs[64 * 64], Ks[64 * 64], Vt[64 * 64], Ps[4 * 16 * 64];
  int blk = blockIdx.x;
  int w = blk >> 3, h = blk & 7;
  int tid = threadIdx.x, lane = tid & 63, wv = tid >> 6;
  int l15 = lane & 15, l4 = lane >> 4;
  const size_t base = (size_t)w * 49 * 1536 + h * 64;
  // stage Q, K (row-major, swizzled); rows >=49 zeroed
#pragma unroll
  for (int i = 0; i < 2; ++i) {
    int j = i * 256 + tid, r = j >> 3, cc = j & 7;
    int off = (r * 128 + cc * 16) ^ ((r & 7) << 4);
    uint4 zq = {0, 0, 0, 0}, zk = {0, 0, 0, 0};
    if (r < 49) {
      zq = *(const uint4*)(qkv + base + (size_t)r * 1536 + cc * 8);
      zk = *(const uint4*)(qkv + base + 512 + (size_t)r * 1536 + cc * 8);
    }
    *(uint4*)((char*)Qs + off) = zq;
    *(uint4*)((char*)Ks + off) = zk;
  }
  // stage V transposed: Vt[c][k] = V[k][c]; swizzle ((c>>3)&7)<<4 (cg varies per lane
  // -> 32-bank spread on the scalar writes; 16B read chunks stay contiguous)
#pragma unroll
  for (int i = 0; i < 2; ++i) {
    int j = i * 256 + tid, r = j >> 3, cg = j & 7;
    if (r < 49) {
      uint4 v = *(const uint4*)(qkv + base + 1024 + (size_t)r * 1536 + cg * 8);
      const bf16* pv = (const bf16*)&v;
#pragma unroll
      for (int e = 0; e < 8; ++e) {
        int c = cg * 8 + e;
        int off = ((c * 64 + r) * 2) ^ (((c >> 3) & 7) << 4);
        *(bf16*)((char*)Vt + off) = pv[e];
      }
    } else {
#pragma unroll
      for (int e = 0; e < 8; ++e) {
        int c = cg * 8 + e;
        int off = ((c * 64 + r) * 2) ^ (((c >> 3) & 7) << 4);
        *(bf16*)((char*)Vt + off) = (bf16)0.0f;
      }
    }
  }
  __syncthreads();
  // S = Q K^T for this wave's 16 rows: S[row=l4*4+reg][col=n*16+l15]
  f32x4 s[4] = {};
#pragma unroll
  for (int kk = 0; kk < 2; ++kk) {
    int rq = wv * 16 + l15;
    bf16x8 aq = *(const bf16x8*)((const char*)Qs +
                ((rq * 128 + kk * 64 + l4 * 16) ^ ((rq & 7) << 4)));
#pragma unroll
    for (int n = 0; n < 4; ++n) {
      int rk = n * 16 + l15;
      bf16x8 bk = *(const bf16x8*)((const char*)Ks +
                  ((rk * 128 + kk * 64 + l4 * 16) ^ ((rk & 7) << 4)));
      s[n] = __builtin_amdgcn_mfma_f32_16x16x32_bf16(aq, bk, s[n], 0, 0, 0);
    }
  }
  // masked softmax per row (reg indexes the row within each 16-lane group)
  float pr[4][4];
#pragma unroll
  for (int reg = 0; reg < 4; ++reg) {
    float m = -1e30f;
#pragma unroll
    for (int n = 0; n < 4; ++n) {
      float v = s[n][reg] * ATT_SCALE;
      if (n * 16 + l15 < 49) m = fmaxf(m, v);
    }
#pragma unroll
    for (int d = 1; d < 16; d <<= 1) m = fmaxf(m, __shfl_xor(m, d));
    float sum = 0.f;
#pragma unroll
    for (int n = 0; n < 4; ++n) {
      float p = (n * 16 + l15 < 49) ? __expf(s[n][reg] * ATT_SCALE - m) : 0.f;
      pr[n][reg] = p;
      sum += p;
    }
#pragma unroll
    for (int d = 1; d < 16; d <<= 1) sum += __shfl_xor(sum, d);
    float inv = 1.f / sum;
#pragma unroll
    for (int n = 0; n < 4; ++n) pr[n][reg] *= inv;
  }
  // write P (bf16) to this wave's private LDS region, swizzled
  char* pbase = (char*)Ps + wv * 2048;
#pragma unroll
  for (int n = 0; n < 4; ++n)
#pragma unroll
    for (int reg = 0; reg < 4; ++reg) {
      int rl = l4 * 4 + reg, col = n * 16 + l15;
      int off = ((rl * 64 + col) * 2) ^ ((rl & 7) << 4);
      *(bf16*)(pbase + off) = (bf16)pr[n][reg];
    }
  __syncthreads();
  // O^T = (V^T)(P^T) via swapped operands: out token = wv*16+l15, d-col = n*16+l4*4+reg
  f32x4 o[4] = {};
#pragma unroll
  for (int kk = 0; kk < 2; ++kk) {
    int rp = l15;
    bf16x8 ap = *(const bf16x8*)(pbase +
                ((rp * 128 + kk * 64 + l4 * 16) ^ ((rp & 7) << 4)));
#pragma unroll
    for (int n = 0; n < 4; ++n) {
      int rv = n * 16 + l15;
      bf16x8 bv = *(const bf16x8*)((const char*)Vt +
                  ((rv * 128 + kk * 64 + l4 * 16) ^ (((rv >> 3) & 7) << 4)));
      o[n] = __builtin_amdgcn_mfma_f32_16x16x32_bf16(bv, ap, o[n], 0, 0, 0);
    }
  }
  // packed 8B stores: attn[tok][512]
  int rl = wv * 16 + l15;
  if (rl < 49) {
    size_t rowoff = ((size_t)w * 49 + rl) * 512 + h * 64;
#pragma unroll
    for (int n = 0; n < 4; ++n) {
      bf16x4 pk;
#pragma unroll
      for (int r = 0; r < 4; ++r) pk[r] = (bf16)o[n][r];
      *(bf16x4*)(attn + rowoff + n * 16 + l4 * 4) = pk;
    }
  }
}

extern "C" void kernel_launch(void* const* d_in, const int* in_sizes, int n_in,
                              void* d_out, int out_size, void* d_ws, size_t ws_size,
                              hipStream_t stream) {
  const float* fmap = (const float*)d_in[0];
  const float* Wq = (const float*)d_in[1];
  const float* Wkv = (const float*)d_in[2];
  const float* Wo = (const float*)d_in[3];
  const float* bo = (const float*)d_in[4];
  float* out = (float*)d_out;
  char* ws = (char*)d_ws;

  // weights live at the front of ws
  const size_t WQKV_B = 1536ull * 256 * 2;  // 786,432
  const size_t WO_B = 256ull * 512 * 2;     // 262,144
  const size_t wbytes = WQKV_B + WO_B;      // 1,048,576

  // pick the largest chunk (fewest chunks) whose buffers fit in ws:
  // per-chunk bytes = Tc*512 (A) + Tc*3072 (qkv) + Tc*1024 (attn) = Tc*4608
  int nc = 0;
  size_t Tc = 0;
  for (int c = 1; c <= 16; c <<= 1) {
    size_t tc = TOK / c;                    // multiple of 6272 = 49*128
    if (wbytes + tc * 4608ull <= ws_size) { nc = c; Tc = tc; break; }
  }
  if (nc == 0) return;  // < ~30 MB workspace: cannot run

  bf16* Wqkv_t = (bf16*)(ws);
  bf16* Wo_t = (bf16*)(ws + WQKV_B);
  bf16* Abuf = (bf16*)(ws + wbytes);
  bf16* qkv = (bf16*)(ws + wbytes + Tc * 512);
  bf16* attn = (bf16*)(ws + wbytes + Tc * 512 + Tc * 3072);

  // weights: Wqkv_t[n][k] = concat(Wq, Wkv) transposed; Wo_t[n][k] = Wo^T
  hipLaunchKernelGGL(transpose_cast_k, dim3(16, 8), dim3(32, 8), 0, stream, Wq, Wqkv_t, 256, 512);
  hipLaunchKernelGGL(transpose_cast_k, dim3(32, 8), dim3(32, 8), 0, stream, Wkv,
                     Wqkv_t + 512 * 256, 256, 1024);
  hipLaunchKernelGGL(transpose_cast_k, dim3(8, 16), dim3(32, 8), 0, stream, Wo, Wo_t, 512, 256);

  for (int c = 0; c < nc; ++c) {
    int tok0 = (int)(c * Tc);
    int wloc = (int)(Tc / 49);  // windows in this chunk
    // fmap -> window-token-major bf16 (chunk rows)
    hipLaunchKernelGGL(cast_partition_k, dim3((int)(Tc / 8)), dim3(256), 0, stream, fmap, Abuf,
                       tok0);
    // qkv = A @ Wqkv   (grid: bn fast axis)
    hipLaunchKernelGGL((gemm_bt_k<256, 1536, 1>), dim3(12, (int)(Tc / 128)), dim3(256), 0, stream,
                       Abuf, Wqkv_t, qkv, nullptr, nullptr, 0);
    // per-window-head attention
    hipLaunchKernelGGL(attn_win_k, dim3(wloc * 8), dim3(256), 0, stream, qkv, attn);
    // out = attn @ Wo + bo, scattered back to (b,56,56,256)
    hipLaunchKernelGGL((gemm_bt_k<512, 256, 2>), dim3(2, (int)(Tc / 128)), dim3(256), 0, stream,
                       attn, Wo_t, nullptr, out, bo, tok0);
  }
}

// Round 4
// 366.539 us; speedup vs baseline: 2.0251x; 2.0251x over previous
//
#include <hip/hip_runtime.h>
#include <hip/hip_bf16.h>

typedef __bf16 bf16;
typedef __bf16 bf16x4 __attribute__((ext_vector_type(4)));
typedef __bf16 bf16x8 __attribute__((ext_vector_type(8)));
typedef float f32x4 __attribute__((ext_vector_type(4)));

#define TOK 100352   // 2048 windows * 49 tokens
#define ATT_SCALE 0.125f

#define GLOAD_LDS16(g, l)                                                        \
  __builtin_amdgcn_global_load_lds((const __attribute__((address_space(1))) void*)(g), \
                                   (__attribute__((address_space(3))) void*)(l), 16, 0, 0)

// ---------------- weight transpose + cast: out[c][r] = bf16(in[r][c]) ----------------
__global__ __launch_bounds__(256) void transpose_cast_k(const float* __restrict__ in,
                                                        bf16* __restrict__ out, int R, int C) {
  __shared__ float t[32][33];
  int c0 = blockIdx.x * 32, r0 = blockIdx.y * 32;
  int tx = threadIdx.x, ty = threadIdx.y;
#pragma unroll
  for (int i = ty; i < 32; i += 8)
    t[i][tx] = in[(size_t)(r0 + i) * C + c0 + tx];
  __syncthreads();
#pragma unroll
  for (int i = ty; i < 32; i += 8)
    out[(size_t)(c0 + i) * R + r0 + tx] = (bf16)t[tx][i];
}

// ---------------- window partition + cast: A[tok_local][256] = bf16(fmap[...]) ----------------
__global__ __launch_bounds__(256) void cast_partition_k(const float* __restrict__ fmap,
                                                        bf16* __restrict__ A, int tok0) {
  int tid = blockIdx.x * 256 + threadIdx.x;
  int tokl = tid >> 5, cg = (tid & 31) << 3;
  int tok = tok0 + tokl;
  int w = tok / 49, t = tok - w * 49;
  int p1 = t / 7, p2 = t - p1 * 7;
  int bb = w >> 6, xx = (w >> 3) & 7, yy = w & 7;
  size_t src = ((((size_t)bb * 56) + xx * 7 + p1) * 56 + yy * 7 + p2) * 256 + cg;
  float4 f0 = *(const float4*)(fmap + src);
  float4 f1 = *(const float4*)(fmap + src + 4);
  bf16x8 o;
  o[0] = (bf16)f0.x; o[1] = (bf16)f0.y; o[2] = (bf16)f0.z; o[3] = (bf16)f0.w;
  o[4] = (bf16)f1.x; o[5] = (bf16)f1.y; o[6] = (bf16)f1.z; o[7] = (bf16)f1.w;
  *(bf16x8*)(A + (size_t)tokl * 256 + cg) = o;
}

// ---------------- GEMM: C[M][ND] = A[M][KD] @ Bt[ND][KD]^T, 128x128 tile, BK=64 ----------------
// Staging via global_load_lds (16B): LDS dest linear (wave base + lane*16); XOR swizzle
// applied to the GLOBAL source address instead (inverse of the read-side swizzle):
//   lds phys o = wv*4096 + i*1024 + lane*16  =>  row r = wv*32+i*8+(lane>>3),
//   source col-chunk cc = (lane&7) ^ ((lane>>3)&7)
// MFMA operands swapped -> transposed fragment: out row = l15, out col = l4*4+reg
// => packed stores. grid = (ND/128, M/128), bn fast.
template <int KD, int ND, int EPI>
__global__ __launch_bounds__(256) void gemm_bt_k(const bf16* __restrict__ A,
                                                 const bf16* __restrict__ Bt,
                                                 bf16* __restrict__ Cb, float* __restrict__ Cf,
                                                 const float* __restrict__ bias, int tok0) {
  __shared__ bf16 As[128 * 64], Bs[128 * 64];
  const int tid = threadIdx.x;
  const int lane = tid & 63, wv = tid >> 6;
  const int l15 = lane & 15, l4 = lane >> 4;
  const int bn = blockIdx.x, bm = blockIdx.y;
  const int mb = (wv >> 1) * 64, nb = (wv & 1) * 64;
  // DMA source addresses (per-lane), dest bases (wave-uniform)
  const int srow = wv * 32 + (lane >> 3);
  const int scol = ((lane & 7) ^ ((lane >> 3) & 7)) * 8;
  const bf16* Ab = A + (size_t)(bm * 128 + srow) * KD + scol;
  const bf16* Bb = Bt + (size_t)(bn * 128 + srow) * KD + scol;
  f32x4 acc[4][4] = {};
  for (int ks = 0; ks < KD / 64; ++ks) {
#pragma unroll
    for (int i = 0; i < 4; ++i) {
      GLOAD_LDS16(Ab + (size_t)i * 8 * KD + ks * 64, As + wv * 2048 + i * 512);
      GLOAD_LDS16(Bb + (size_t)i * 8 * KD + ks * 64, Bs + wv * 2048 + i * 512);
    }
    __syncthreads();  // drains vmcnt -> LDS tile ready for all waves
#pragma unroll
    for (int kk = 0; kk < 2; ++kk) {
      bf16x8 af[4], bfr[4];
#pragma unroll
      for (int m = 0; m < 4; ++m) {
        int r = mb + m * 16 + l15;
        af[m] = *(const bf16x8*)((const char*)As +
                 ((r * 128 + kk * 64 + l4 * 16) ^ ((r & 7) << 4)));
      }
#pragma unroll
      for (int n = 0; n < 4; ++n) {
        int r = nb + n * 16 + l15;
        bfr[n] = *(const bf16x8*)((const char*)Bs +
                 ((r * 128 + kk * 64 + l4 * 16) ^ ((r & 7) << 4)));
      }
#pragma unroll
      for (int m = 0; m < 4; ++m)
#pragma unroll
        for (int n = 0; n < 4; ++n)
          acc[m][n] = __builtin_amdgcn_mfma_f32_16x16x32_bf16(bfr[n], af[m], acc[m][n], 0, 0, 0);
    }
    __syncthreads();  // compute done before next DMA overwrites
  }
  if constexpr (EPI == 1) {
#pragma unroll
    for (int m = 0; m < 4; ++m) {
      size_t row = (size_t)bm * 128 + mb + m * 16 + l15;
#pragma unroll
      for (int n = 0; n < 4; ++n) {
        int col = bn * 128 + nb + n * 16 + l4 * 4;
        bf16x4 pk;
#pragma unroll
        for (int r = 0; r < 4; ++r) pk[r] = (bf16)acc[m][n][r];
        *(bf16x4*)(Cb + row * ND + col) = pk;
      }
    }
  } else {
#pragma unroll
    for (int m = 0; m < 4; ++m) {
      int tok = tok0 + bm * 128 + mb + m * 16 + l15;
      int w = tok / 49, t = tok - w * 49;
      int p1 = t / 7, p2 = t - p1 * 7;
      int bb = w >> 6, xx = (w >> 3) & 7, yy = w & 7;
      size_t orow = (((size_t)bb * 56) + xx * 7 + p1) * 56 + yy * 7 + p2;
#pragma unroll
      for (int n = 0; n < 4; ++n) {
        int col = bn * 128 + nb + n * 16 + l4 * 4;
        float4 b4 = *(const float4*)(bias + col);
        float4 v;
        v.x = acc[m][n][0] + b4.x;
        v.y = acc[m][n][1] + b4.y;
        v.z = acc[m][n][2] + b4.z;
        v.w = acc[m][n][3] + b4.w;
        *(float4*)(Cf + orow * 256 + col) = v;
      }
    }
  }
}

// ---------------- attention: one block per (window_local, head) ----------------
__global__ __launch_bounds__(256) void attn_win_k(const bf16* __restrict__ qkv,
                                                  bf16* __restrict__ attn) {
  __shared__ bf16 Qs[64 * 64], Ks[64 * 64], Vt[64 * 64], Ps[4 * 16 * 64];
  int blk = blockIdx.x;
  int w = blk >> 3, h = blk & 7;
  int tid = threadIdx.x, lane = tid & 63, wv = tid >> 6;
  int l15 = lane & 15, l4 = lane >> 4;
  const size_t base = (size_t)w * 49 * 1536 + h * 64;
  // stage Q, K (row-major, swizzled); rows >=49 zeroed
#pragma unroll
  for (int i = 0; i < 2; ++i) {
    int j = i * 256 + tid, r = j >> 3, cc = j & 7;
    int off = (r * 128 + cc * 16) ^ ((r & 7) << 4);
    uint4 zq = {0, 0, 0, 0}, zk = {0, 0, 0, 0};
    if (r < 49) {
      zq = *(const uint4*)(qkv + base + (size_t)r * 1536 + cc * 8);
      zk = *(const uint4*)(qkv + base + 512 + (size_t)r * 1536 + cc * 8);
    }
    *(uint4*)((char*)Qs + off) = zq;
    *(uint4*)((char*)Ks + off) = zk;
  }
  // stage V transposed: Vt[c][k] = V[k][c]; swizzle ((c>>3)&7)<<4
#pragma unroll
  for (int i = 0; i < 2; ++i) {
    int j = i * 256 + tid, r = j >> 3, cg = j & 7;
    if (r < 49) {
      uint4 v = *(const uint4*)(qkv + base + 1024 + (size_t)r * 1536 + cg * 8);
      const bf16* pv = (const bf16*)&v;
#pragma unroll
      for (int e = 0; e < 8; ++e) {
        int c = cg * 8 + e;
        int off = ((c * 64 + r) * 2) ^ (((c >> 3) & 7) << 4);
        *(bf16*)((char*)Vt + off) = pv[e];
      }
    } else {
#pragma unroll
      for (int e = 0; e < 8; ++e) {
        int c = cg * 8 + e;
        int off = ((c * 64 + r) * 2) ^ (((c >> 3) & 7) << 4);
        *(bf16*)((char*)Vt + off) = (bf16)0.0f;
      }
    }
  }
  __syncthreads();
  // S = Q K^T for this wave's 16 rows: S[row=l4*4+reg][col=n*16+l15]
  f32x4 s[4] = {};
#pragma unroll
  for (int kk = 0; kk < 2; ++kk) {
    int rq = wv * 16 + l15;
    bf16x8 aq = *(const bf16x8*)((const char*)Qs +
                ((rq * 128 + kk * 64 + l4 * 16) ^ ((rq & 7) << 4)));
#pragma unroll
    for (int n = 0; n < 4; ++n) {
      int rk = n * 16 + l15;
      bf16x8 bk = *(const bf16x8*)((const char*)Ks +
                  ((rk * 128 + kk * 64 + l4 * 16) ^ ((rk & 7) << 4)));
      s[n] = __builtin_amdgcn_mfma_f32_16x16x32_bf16(aq, bk, s[n], 0, 0, 0);
    }
  }
  // masked softmax per row
  float pr[4][4];
#pragma unroll
  for (int reg = 0; reg < 4; ++reg) {
    float m = -1e30f;
#pragma unroll
    for (int n = 0; n < 4; ++n) {
      float v = s[n][reg] * ATT_SCALE;
      if (n * 16 + l15 < 49) m = fmaxf(m, v);
    }
#pragma unroll
    for (int d = 1; d < 16; d <<= 1) m = fmaxf(m, __shfl_xor(m, d));
    float sum = 0.f;
#pragma unroll
    for (int n = 0; n < 4; ++n) {
      float p = (n * 16 + l15 < 49) ? __expf(s[n][reg] * ATT_SCALE - m) : 0.f;
      pr[n][reg] = p;
      sum += p;
    }
#pragma unroll
    for (int d = 1; d < 16; d <<= 1) sum += __shfl_xor(sum, d);
    float inv = 1.f / sum;
#pragma unroll
    for (int n = 0; n < 4; ++n) pr[n][reg] *= inv;
  }
  // write P (bf16) to this wave's private LDS region, swizzled
  char* pbase = (char*)Ps + wv * 2048;
#pragma unroll
  for (int n = 0; n < 4; ++n)
#pragma unroll
    for (int reg = 0; reg < 4; ++reg) {
      int rl = l4 * 4 + reg, col = n * 16 + l15;
      int off = ((rl * 64 + col) * 2) ^ ((rl & 7) << 4);
      *(bf16*)(pbase + off) = (bf16)pr[n][reg];
    }
  __syncthreads();
  // O^T = (V^T)(P^T): out token = wv*16+l15, d-col = n*16+l4*4+reg
  f32x4 o[4] = {};
#pragma unroll
  for (int kk = 0; kk < 2; ++kk) {
    int rp = l15;
    bf16x8 ap = *(const bf16x8*)(pbase +
                ((rp * 128 + kk * 64 + l4 * 16) ^ ((rp & 7) << 4)));
#pragma unroll
    for (int n = 0; n < 4; ++n) {
      int rv = n * 16 + l15;
      bf16x8 bv = *(const bf16x8*)((const char*)Vt +
                  ((rv * 128 + kk * 64 + l4 * 16) ^ (((rv >> 3) & 7) << 4)));
      o[n] = __builtin_amdgcn_mfma_f32_16x16x32_bf16(bv, ap, o[n], 0, 0, 0);
    }
  }
  // packed 8B stores: attn[tok][512]
  int rl = wv * 16 + l15;
  if (rl < 49) {
    size_t rowoff = ((size_t)w * 49 + rl) * 512 + h * 64;
#pragma unroll
    for (int n = 0; n < 4; ++n) {
      bf16x4 pk;
#pragma unroll
      for (int r = 0; r < 4; ++r) pk[r] = (bf16)o[n][r];
      *(bf16x4*)(attn + rowoff + n * 16 + l4 * 4) = pk;
    }
  }
}

extern "C" void kernel_launch(void* const* d_in, const int* in_sizes, int n_in,
                              void* d_out, int out_size, void* d_ws, size_t ws_size,
                              hipStream_t stream) {
  const float* fmap = (const float*)d_in[0];
  const float* Wq = (const float*)d_in[1];
  const float* Wkv = (const float*)d_in[2];
  const float* Wo = (const float*)d_in[3];
  const float* bo = (const float*)d_in[4];
  float* out = (float*)d_out;
  char* ws = (char*)d_ws;

  const size_t WQKV_B = 1536ull * 256 * 2;
  const size_t WO_B = 256ull * 512 * 2;
  const size_t wbytes = WQKV_B + WO_B;

  int nc = 0;
  size_t Tc = 0;
  for (int c = 1; c <= 16; c <<= 1) {
    size_t tc = TOK / c;
    if (wbytes + tc * 4608ull <= ws_size) { nc = c; Tc = tc; break; }
  }
  if (nc == 0) return;

  bf16* Wqkv_t = (bf16*)(ws);
  bf16* Wo_t = (bf16*)(ws + WQKV_B);
  bf16* Abuf = (bf16*)(ws + wbytes);
  bf16* qkv = (bf16*)(ws + wbytes + Tc * 512);
  bf16* attn = (bf16*)(ws + wbytes + Tc * 512 + Tc * 3072);

  hipLaunchKernelGGL(transpose_cast_k, dim3(16, 8), dim3(32, 8), 0, stream, Wq, Wqkv_t, 256, 512);
  hipLaunchKernelGGL(transpose_cast_k, dim3(32, 8), dim3(32, 8), 0, stream, Wkv,
                     Wqkv_t + 512 * 256, 256, 1024);
  hipLaunchKernelGGL(transpose_cast_k, dim3(8, 16), dim3(32, 8), 0, stream, Wo, Wo_t, 512, 256);

  for (int c = 0; c < nc; ++c) {
    int tok0 = (int)(c * Tc);
    int wloc = (int)(Tc / 49);
    hipLaunchKernelGGL(cast_partition_k, dim3((int)(Tc / 8)), dim3(256), 0, stream, fmap, Abuf,
                       tok0);
    hipLaunchKernelGGL((gemm_bt_k<256, 1536, 1>), dim3(12, (int)(Tc / 128)), dim3(256), 0, stream,
                       Abuf, Wqkv_t, qkv, nullptr, nullptr, 0);
    hipLaunchKernelGGL(attn_win_k, dim3(wloc * 8), dim3(256), 0, stream, qkv, attn);
    hipLaunchKernelGGL((gemm_bt_k<512, 256, 2>), dim3(2, (int)(Tc / 128)), dim3(256), 0, stream,
                       attn, Wo_t, nullptr, out, bo, tok0);
  }
}